// Round 3
// baseline (309.268 us; speedup 1.0000x reference)
//
#include <hip/hip_runtime.h>

#define D_MODEL 1024
#define N_HEADS 16
#define DK 64
#define LSEQ 512
#define BATCH 4
#define M_ROWS (BATCH * LSEQ)   // 2048

typedef unsigned short ushort_t;
typedef __attribute__((ext_vector_type(8))) short short8;
typedef __attribute__((ext_vector_type(4))) float floatx4;

__device__ __forceinline__ float bf2f(unsigned short u) {
    return __uint_as_float(((unsigned int)u) << 16);
}
__device__ __forceinline__ unsigned short f2bf(float f) {
    unsigned int u = __float_as_uint(f);
    u += 0x7fffu + ((u >> 16) & 1u);   // round-to-nearest-even
    return (unsigned short)(u >> 16);
}

// ---------------------------------------------------------------------------
// cast3: three fp32 arrays -> bf16, 4 elems/thread. grid (n/1024, 3)
// ---------------------------------------------------------------------------
__global__ __launch_bounds__(256) void cast3_kernel(
    const float* __restrict__ a, const float* __restrict__ b,
    const float* __restrict__ c, ushort_t* __restrict__ oa,
    ushort_t* __restrict__ ob, ushort_t* __restrict__ oc, int n)
{
    const float* src = (blockIdx.y == 0) ? a : (blockIdx.y == 1) ? b : c;
    ushort_t* dst = (blockIdx.y == 0) ? oa : (blockIdx.y == 1) ? ob : oc;
    int i = (blockIdx.x * 256 + threadIdx.x) * 4;
    if (i + 3 < n) {
        float4 v = *(const float4*)(src + i);
        ushort4 o = make_ushort4(f2bf(v.x), f2bf(v.y), f2bf(v.z), f2bf(v.w));
        *(ushort4*)(dst + i) = o;
    }
}

// ---------------------------------------------------------------------------
// transpose4: W[k][n] fp32 (1024x1024) -> Wt[n][k] bf16, for 4 weights.
// ---------------------------------------------------------------------------
__global__ __launch_bounds__(256) void transpose4_kernel(
    const float* __restrict__ w0, const float* __restrict__ w1,
    const float* __restrict__ w2, const float* __restrict__ w3,
    ushort_t* __restrict__ o0, ushort_t* __restrict__ o1,
    ushort_t* __restrict__ o2, ushort_t* __restrict__ o3)
{
    __shared__ float tile[32][33];
    const float* W = (blockIdx.z == 0) ? w0 : (blockIdx.z == 1) ? w1
                   : (blockIdx.z == 2) ? w2 : w3;
    ushort_t* O = (blockIdx.z == 0) ? o0 : (blockIdx.z == 1) ? o1
                : (blockIdx.z == 2) ? o2 : o3;
    const int tx = threadIdx.x & 31;
    const int ty = threadIdx.x >> 5;
    const int kbase = blockIdx.y * 32;
    const int nbase = blockIdx.x * 32;
    #pragma unroll
    for (int j = 0; j < 4; ++j)
        tile[ty + 8 * j][tx] = W[(size_t)(kbase + ty + 8 * j) * 1024 + nbase + tx];
    __syncthreads();
    #pragma unroll
    for (int j = 0; j < 4; ++j) {
        int n = nbase + ty + 8 * j;
        O[(size_t)n * 1024 + kbase + tx] = f2bf(tile[tx][ty + 8 * j]);
    }
}

// ---------------------------------------------------------------------------
// bf16 MFMA GEMM body (B^T layout): out = A @ Bt^T [+ bvec] [+ res]
// BM=BN=64, BK=64, 256 threads, wave-tile 32x32 (2x2x2 of 16x16x32).
// OUT_VT: write output TRANSPOSED as vT[(b*16+h)][d][l] bf16 (b=row>>9,
// l=row&511, h=col>>6, d=col&63) -- feeds attention pass 2 with barrier-free
// global V^T fragment reads. 4 consecutive rows pack into one 8B store.
// ---------------------------------------------------------------------------
template <bool OUT_BF16, bool ADD_BVEC, bool ADD_RES, bool OUT_VT>
__device__ __forceinline__ void gemm_bt_body(
    const ushort_t* __restrict__ A, const ushort_t* __restrict__ Bt,
    const float* __restrict__ bvec, const float* __restrict__ res,
    void* __restrict__ outp, int N, int K, int kStart, int kEnd,
    int rowBase, int colBase, ushort_t* As, ushort_t* Bs)
{
    const int tid = threadIdx.x;
    const int l = tid & 63;
    const int w = tid >> 6;
    const int wave_m = w >> 1;
    const int wave_n = w & 1;

    const int srow8 = l >> 3;
    const int cgl = ((l & 7) + srow8) & 7;        // global k-chunk
    const ushort_t* gA0 = A  + (size_t)(rowBase + w * 16 + 0 + srow8) * K + cgl * 8;
    const ushort_t* gA1 = A  + (size_t)(rowBase + w * 16 + 8 + srow8) * K + cgl * 8;
    const ushort_t* gB0 = Bt + (size_t)(colBase + w * 16 + 0 + srow8) * K + cgl * 8;
    const ushort_t* gB1 = Bt + (size_t)(colBase + w * 16 + 8 + srow8) * K + cgl * 8;
    ushort_t* lA0 = As + w * 1024;
    ushort_t* lA1 = As + w * 1024 + 512;
    ushort_t* lB0 = Bs + w * 1024;
    ushort_t* lB1 = Bs + w * 1024 + 512;

    floatx4 acc[2][2];
    #pragma unroll
    for (int i = 0; i < 2; ++i)
        #pragma unroll
        for (int j = 0; j < 2; ++j)
            acc[i][j] = (floatx4){0.f, 0.f, 0.f, 0.f};

    const int fm = l & 15;
    const int fg = l >> 4;

    for (int k0 = kStart; k0 < kEnd; k0 += 64) {
        __builtin_amdgcn_global_load_lds(
            (const __attribute__((address_space(1))) void*)(gA0 + k0),
            (__attribute__((address_space(3))) void*)lA0, 16, 0, 0);
        __builtin_amdgcn_global_load_lds(
            (const __attribute__((address_space(1))) void*)(gA1 + k0),
            (__attribute__((address_space(3))) void*)lA1, 16, 0, 0);
        __builtin_amdgcn_global_load_lds(
            (const __attribute__((address_space(1))) void*)(gB0 + k0),
            (__attribute__((address_space(3))) void*)lB0, 16, 0, 0);
        __builtin_amdgcn_global_load_lds(
            (const __attribute__((address_space(1))) void*)(gB1 + k0),
            (__attribute__((address_space(3))) void*)lB1, 16, 0, 0);
        __syncthreads();

        short8 afrag[2][2], bfrag[2][2];
        #pragma unroll
        for (int mi = 0; mi < 2; ++mi)
            #pragma unroll
            for (int kt = 0; kt < 2; ++kt) {
                int p = ((kt * 4 + fg) - fm) & 7;
                afrag[mi][kt] = *(const short8*)
                    &As[(wave_m * 32 + mi * 16 + fm) * 64 + p * 8];
            }
        #pragma unroll
        for (int ni = 0; ni < 2; ++ni)
            #pragma unroll
            for (int kt = 0; kt < 2; ++kt) {
                int p = ((kt * 4 + fg) - fm) & 7;
                bfrag[ni][kt] = *(const short8*)
                    &Bs[(wave_n * 32 + ni * 16 + fm) * 64 + p * 8];
            }

        #pragma unroll
        for (int kt = 0; kt < 2; ++kt)
            #pragma unroll
            for (int mi = 0; mi < 2; ++mi)
                #pragma unroll
                for (int ni = 0; ni < 2; ++ni)
                    acc[mi][ni] = __builtin_amdgcn_mfma_f32_16x16x32_bf16(
                        afrag[mi][kt], bfrag[ni][kt], acc[mi][ni], 0, 0, 0);
        __syncthreads();
    }

    const int crow0 = rowBase + wave_m * 32 + fg * 4;
    const int ccol0 = colBase + wave_n * 32 + fm;
    #pragma unroll
    for (int mi = 0; mi < 2; ++mi) {
        #pragma unroll
        for (int ni = 0; ni < 2; ++ni) {
            const int col = ccol0 + ni * 16;
            const float bb = ADD_BVEC ? bvec[col] : 0.f;
            if (OUT_VT) {
                const int row0 = crow0 + mi * 16;   // rows row0..row0+3
                ushort4 pk;
                pk.x = f2bf(acc[mi][ni][0] + bb);
                pk.y = f2bf(acc[mi][ni][1] + bb);
                pk.z = f2bf(acc[mi][ni][2] + bb);
                pk.w = f2bf(acc[mi][ni][3] + bb);
                const size_t base =
                    ((size_t)((row0 >> 9) * 16 + (col >> 6)) * 64 + (col & 63)) * 512;
                *(ushort4*)&((ushort_t*)outp)[base + (row0 & 511)] = pk;
            } else {
                #pragma unroll
                for (int r = 0; r < 4; ++r) {
                    const int row = crow0 + mi * 16 + r;
                    float v = acc[mi][ni][r] + bb;
                    if (ADD_RES) v += res[(size_t)row * N + col];
                    if (OUT_BF16)
                        ((ushort_t*)outp)[(size_t)row * N + col] = f2bf(v);
                    else
                        ((float*)outp)[(size_t)row * N + col] = v;
                }
            }
        }
    }
}

// Batched QKV projection: blockIdx.z selects (A, Bt, bias, out). 1536 blocks.
// z==2 (V projection) writes its output transposed per-head (OUT_VT).
__global__ __launch_bounds__(256) void gemm_qkv(
    const ushort_t* a0, const ushort_t* a1, const ushort_t* a2,
    const ushort_t* t0, const ushort_t* t1, const ushort_t* t2,
    const float* b0, const float* b1, const float* b2,
    ushort_t* o0, ushort_t* o1, ushort_t* o2)
{
    __shared__ ushort_t As[64 * 64];
    __shared__ ushort_t Bs[64 * 64];
    const int z = blockIdx.z;
    if (z == 2) {
        gemm_bt_body<true, true, false, true>(a2, t2, b2, nullptr, o2, D_MODEL,
                                              D_MODEL, 0, D_MODEL,
                                              blockIdx.y * 64, blockIdx.x * 64, As, Bs);
    } else {
        const ushort_t* A  = (z == 0) ? a0 : a1;
        const ushort_t* Bt = (z == 0) ? t0 : t1;
        const float* bv    = (z == 0) ? b0 : b1;
        ushort_t* o        = (z == 0) ? o0 : o1;
        gemm_bt_body<true, true, false, false>(A, Bt, bv, nullptr, o, D_MODEL,
                                               D_MODEL, 0, D_MODEL,
                                               blockIdx.y * 64, blockIdx.x * 64, As, Bs);
    }
}

// Final projection, split-K x2.
__global__ __launch_bounds__(256) void gemm_out(
    const ushort_t* __restrict__ A, const ushort_t* __restrict__ Bt,
    const float* __restrict__ bvec, const float* __restrict__ res,
    float* __restrict__ out0, float* __restrict__ out1)
{
    __shared__ ushort_t As[64 * 64];
    __shared__ ushort_t Bs[64 * 64];
    if (blockIdx.z == 0)
        gemm_bt_body<false, true, true, false>(A, Bt, bvec, res, out0, D_MODEL,
                                               D_MODEL, 0, 512,
                                               blockIdx.y * 64, blockIdx.x * 64, As, Bs);
    else
        gemm_bt_body<false, false, false, false>(A, Bt, nullptr, nullptr, out1, D_MODEL,
                                                 D_MODEL, 512, 1024,
                                                 blockIdx.y * 64, blockIdx.x * 64, As, Bs);
}

// ---------------------------------------------------------------------------
// MFMA attention v4: block = 16 q-rows x one (b,h). 256 threads (4 waves).
// KEY CHANGE vs v2/v3: pass 2's per-tile LDS V-transpose (2 barriers x 8
// tiles, the dominant stall: ~18k cyc/block of barrier drains) is GONE.
// V^T is materialized globally by gemm_qkv (OUT_VT) and pass 2 reads V^T
// fragments straight from global (L2-hot, 64KB/bh shared by 32 blocks),
// mirroring pass 1's barrier-free K reads. 3 barriers/block total.
// LDS ~19.5KB, launch_bounds(256,5) -> 5 blocks/CU (20 waves) of TLP.
// Grid: (LSEQ/16, BATCH*N_HEADS) = (32, 64).
// ---------------------------------------------------------------------------
#define P_STRIDE 520   // ushorts; 1040B row => row-start banks rotate by 4

__global__ __launch_bounds__(256, 5) void attn_mfma(
    const ushort_t* __restrict__ qh, const ushort_t* __restrict__ kh,
    const ushort_t* __restrict__ vt, const float* __restrict__ bias,
    const float* __restrict__ gbias, ushort_t* __restrict__ ctx)
{
    __shared__ __attribute__((aligned(16))) ushort_t Qs[16 * 72];
    __shared__ __attribute__((aligned(16))) ushort_t P[16 * P_STRIDE];
    __shared__ float redm[4][16];
    __shared__ float reds[4][16];

    const int tid = threadIdx.x;
    const int l = tid & 63;
    const int w = tid >> 6;
    const int m = l & 15;
    const int g = l >> 4;

    const int bh = blockIdx.y;
    const int h = bh & (N_HEADS - 1);
    const int b = bh >> 4;
    const int q0 = blockIdx.x * 16;

    const ushort_t* Qg = qh + ((size_t)(b * LSEQ + q0)) * D_MODEL + h * DK;
    const ushort_t* Kg = kh + ((size_t)(b * LSEQ)) * D_MODEL + h * DK;
    const ushort_t* Vt_g = vt + (size_t)bh * DK * LSEQ;   // [64][512] bf16

    // ---- stage Q tile (16 x 64 bf16) ----
    if (tid < 128) {
        int row = tid >> 3, seg = tid & 7;
        short8 t = *(const short8*)(Qg + (size_t)row * D_MODEL + seg * 8);
        *(short8*)&Qs[row * 72 + seg * 8] = t;
    }
    __syncthreads();

    short8 aq0 = *(const short8*)&Qs[m * 72 + g * 8];
    short8 aq1 = *(const short8*)&Qs[m * 72 + g * 8 + 32];

    // ---- pass 1: S = QK^T (K direct from global, no barriers) ----
    floatx4 acc[8];
    #pragma unroll 2
    for (int it = 0; it < 8; ++it) {
        const int kb = it * 64 + w * 16;
        const ushort_t* kr = Kg + (size_t)(kb + m) * D_MODEL + g * 8;
        short8 bk0 = *(const short8*)kr;
        short8 bk1 = *(const short8*)(kr + 32);
        floatx4 a = (floatx4){0.f, 0.f, 0.f, 0.f};
        a = __builtin_amdgcn_mfma_f32_16x16x32_bf16(aq0, bk0, a, 0, 0, 0);
        a = __builtin_amdgcn_mfma_f32_16x16x32_bf16(aq1, bk1, a, 0, 0, 0);
        acc[it] = a;
    }

    // ---- bias + gbias in MFMA C-layout: thread (w,g,m) owns
    // rows g*4+r, cols it*64 + w*16 + m. 64 independent dword loads. ----
    const float* bp = bias  + ((size_t)bh * LSEQ + q0) * LSEQ + w * 16 + m;
    const float* gp = gbias + ((size_t)bh * LSEQ + q0) * LSEQ + w * 16 + m;
    float bsum[8][4];
    #pragma unroll
    for (int it = 0; it < 8; ++it)
        #pragma unroll
        for (int r = 0; r < 4; ++r) {
            const size_t off = (size_t)(g * 4 + r) * LSEQ + it * 64;
            bsum[it][r] = bp[off] + gp[off];
        }
    #pragma unroll
    for (int it = 0; it < 8; ++it)
        #pragma unroll
        for (int r = 0; r < 4; ++r)
            acc[it][r] = acc[it][r] * 0.125f + bsum[it][r];

    // ---- softmax in MFMA layout ----
    float mx[4];
    #pragma unroll
    for (int r = 0; r < 4; ++r) {
        float pm = fmaxf(
            fmaxf(fmaxf(acc[0][r], acc[1][r]), fmaxf(acc[2][r], acc[3][r])),
            fmaxf(fmaxf(acc[4][r], acc[5][r]), fmaxf(acc[6][r], acc[7][r])));
        #pragma unroll
        for (int d = 1; d < 16; d <<= 1)
            pm = fmaxf(pm, __shfl_xor(pm, d, 64));
        mx[r] = pm;
    }
    if (m == 0) {
        #pragma unroll
        for (int r = 0; r < 4; ++r) redm[w][g * 4 + r] = mx[r];
    }
    __syncthreads();
    #pragma unroll
    for (int r = 0; r < 4; ++r)
        mx[r] = fmaxf(fmaxf(redm[0][g * 4 + r], redm[1][g * 4 + r]),
                      fmaxf(redm[2][g * 4 + r], redm[3][g * 4 + r]));

    float sm[4] = {0.f, 0.f, 0.f, 0.f};
    #pragma unroll
    for (int it = 0; it < 8; ++it)
        #pragma unroll
        for (int r = 0; r < 4; ++r) {
            float e = __expf(acc[it][r] - mx[r]);
            sm[r] += e;
            P[(g * 4 + r) * P_STRIDE + it * 64 + w * 16 + m] = f2bf(e);
        }
    #pragma unroll
    for (int r = 0; r < 4; ++r) {
        #pragma unroll
        for (int d = 1; d < 16; d <<= 1)
            sm[r] += __shfl_xor(sm[r], d, 64);
    }
    if (m == 0) {
        #pragma unroll
        for (int r = 0; r < 4; ++r) reds[w][g * 4 + r] = sm[r];
    }
    __syncthreads();   // publishes P + reds
    float rinv[4];
    #pragma unroll
    for (int r = 0; r < 4; ++r)
        rinv[r] = 1.0f / (reds[0][g * 4 + r] + reds[1][g * 4 + r] +
                          reds[2][g * 4 + r] + reds[3][g * 4 + r]);

    // ---- pass 2: ctx = P V. P from LDS, V^T direct from global.
    // Barrier-free: mirrors pass 1. Wave w owns output cols w*16+m. ----
    floatx4 oacc = (floatx4){0.f, 0.f, 0.f, 0.f};
    const ushort_t* vrow = Vt_g + (size_t)(w * 16 + m) * LSEQ + g * 8;
    const ushort_t* prow = &P[(size_t)m * P_STRIDE + g * 8];
    #pragma unroll 2
    for (int vtile = 0; vtile < 8; ++vtile) {
        #pragma unroll
        for (int kt = 0; kt < 2; ++kt) {
            const int ko = vtile * 64 + kt * 32;
            short8 pf = *(const short8*)(prow + ko);
            short8 vf = *(const short8*)(vrow + ko);
            oacc = __builtin_amdgcn_mfma_f32_16x16x32_bf16(pf, vf, oacc, 0, 0, 0);
        }
    }

    // ---- epilogue: row g*4+r matches rinv[r] held in this lane ----
    {
        const int qrow0 = g * 4;
        const int dcol = w * 16 + m;
        ushort_t* cp = ctx + ((size_t)(b * LSEQ + q0 + qrow0)) * D_MODEL + h * DK + dcol;
        #pragma unroll
        for (int r = 0; r < 4; ++r)
            cp[(size_t)r * D_MODEL] = f2bf(oacc[r] * rinv[r]);
    }
}

// ---------------------------------------------------------------------------
// LayerNorm over D=1024: x = LN(x + part2). One block per row.
// ---------------------------------------------------------------------------
__global__ __launch_bounds__(256) void ln_kernel(
    float* __restrict__ x, const float* __restrict__ part2,
    const float* __restrict__ g, const float* __restrict__ beta)
{
    const int row = blockIdx.x;
    float* xr = x + (size_t)row * D_MODEL;
    const float* pr = part2 + (size_t)row * D_MODEL;
    const int tid = threadIdx.x;

    float v[4];
    float s = 0.f, sq = 0.f;
    #pragma unroll
    for (int j = 0; j < 4; ++j) {
        v[j] = xr[tid + 256 * j] + pr[tid + 256 * j];
        s += v[j];
        sq += v[j] * v[j];
    }
    __shared__ float rs[256], rq[256];
    rs[tid] = s;
    rq[tid] = sq;
    __syncthreads();
    for (int st = 128; st > 0; st >>= 1) {
        if (tid < st) { rs[tid] += rs[tid + st]; rq[tid] += rq[tid + st]; }
        __syncthreads();
    }
    const float mean = rs[0] * (1.0f / D_MODEL);
    const float var = rq[0] * (1.0f / D_MODEL) - mean * mean;
    const float rinv = rsqrtf(var + 1e-6f);
    #pragma unroll
    for (int j = 0; j < 4; ++j) {
        int n = tid + 256 * j;
        xr[n] = (v[j] - mean) * rinv * g[n] + beta[n];
    }
}

// ---------------------------------------------------------------------------
extern "C" void kernel_launch(void* const* d_in, const int* in_sizes, int n_in,
                              void* d_out, int out_size, void* d_ws, size_t ws_size,
                              hipStream_t stream)
{
    const float* q     = (const float*)d_in[0];
    const float* k     = (const float*)d_in[1];
    const float* v     = (const float*)d_in[2];
    const float* bias  = (const float*)d_in[3];
    const float* gbias = (const float*)d_in[4];
    const float* wq    = (const float*)d_in[5];
    const float* bq    = (const float*)d_in[6];
    const float* wk    = (const float*)d_in[7];
    const float* bk    = (const float*)d_in[8];
    const float* wv    = (const float*)d_in[9];
    const float* bv    = (const float*)d_in[10];
    const float* wo    = (const float*)d_in[11];
    const float* bo    = (const float*)d_in[12];
    const float* ln_g  = (const float*)d_in[13];
    const float* ln_b  = (const float*)d_in[14];

    const size_t MB = 1u << 20;
    char* wsb = (char*)d_ws;
    ushort_t* vb   = (ushort_t*)(wsb + 0 * MB);    // 4 MB
    ushort_t* wqb  = (ushort_t*)(wsb + 4 * MB);    // 2 MB each
    ushort_t* wkb  = (ushort_t*)(wsb + 6 * MB);
    ushort_t* wvb  = (ushort_t*)(wsb + 8 * MB);
    ushort_t* wob  = (ushort_t*)(wsb + 10 * MB);
    ushort_t* qhb  = (ushort_t*)(wsb + 12 * MB);   // 4 MB each
    ushort_t* khb  = (ushort_t*)(wsb + 16 * MB);
    ushort_t* vtb  = (ushort_t*)(wsb + 20 * MB);   // V^T [bh][64][512]
    ushort_t* ctxb = (ushort_t*)(wsb + 24 * MB);
    // out1 (8 MB fp32) overlays qhb+khb — both dead once attn completes.
    float* out1 = (float*)(wsb + 12 * MB);
    // d_out doubles as qb/kb scratch; dead before gemm_out writes d_out.
    ushort_t* qb = (ushort_t*)d_out;
    ushort_t* kb = (ushort_t*)d_out + (size_t)M_ROWS * D_MODEL;
    float* outp = (float*)d_out;

    const int NELEM = M_ROWS * D_MODEL;

    cast3_kernel<<<dim3(NELEM / 1024, 3), 256, 0, stream>>>(
        q, k, v, qb, kb, vb, NELEM);
    transpose4_kernel<<<dim3(32, 32, 4), 256, 0, stream>>>(
        wq, wk, wv, wo, wqb, wkb, wvb, wob);

    dim3 gqkv(D_MODEL / 64, M_ROWS / 64, 3);  // 1536 blocks
    gemm_qkv<<<gqkv, 256, 0, stream>>>(
        qb, kb, vb, wqb, wkb, wvb, bq, bk, bv, qhb, khb, vtb);

    dim3 ablk(LSEQ / 16, BATCH * N_HEADS);    // 2048 blocks
    attn_mfma<<<ablk, 256, 0, stream>>>(qhb, khb, vtb, bias, gbias, ctxb);

    dim3 gout(D_MODEL / 64, M_ROWS / 64, 2);  // 1024 blocks (split-K x2)
    gemm_out<<<gout, 256, 0, stream>>>(ctxb, wob, bo, q, outp, out1);

    ln_kernel<<<M_ROWS, 256, 0, stream>>>(outp, out1, ln_g, ln_b);
}

// Round 4
// 266.659 us; speedup vs baseline: 1.1598x; 1.1598x over previous
//
#include <hip/hip_runtime.h>

#define D_MODEL 1024
#define N_HEADS 16
#define DK 64
#define LSEQ 512
#define BATCH 4
#define M_ROWS (BATCH * LSEQ)   // 2048

typedef unsigned short ushort_t;
typedef __attribute__((ext_vector_type(8))) short short8;
typedef __attribute__((ext_vector_type(4))) float floatx4;

__device__ __forceinline__ float bf2f(unsigned short u) {
    return __uint_as_float(((unsigned int)u) << 16);
}
__device__ __forceinline__ unsigned short f2bf(float f) {
    unsigned int u = __float_as_uint(f);
    u += 0x7fffu + ((u >> 16) & 1u);   // round-to-nearest-even
    return (unsigned short)(u >> 16);
}

// ---------------------------------------------------------------------------
// cast3: three fp32 arrays -> bf16, 4 elems/thread. grid (n/1024, 3)
// ---------------------------------------------------------------------------
__global__ __launch_bounds__(256) void cast3_kernel(
    const float* __restrict__ a, const float* __restrict__ b,
    const float* __restrict__ c, ushort_t* __restrict__ oa,
    ushort_t* __restrict__ ob, ushort_t* __restrict__ oc, int n)
{
    const float* src = (blockIdx.y == 0) ? a : (blockIdx.y == 1) ? b : c;
    ushort_t* dst = (blockIdx.y == 0) ? oa : (blockIdx.y == 1) ? ob : oc;
    int i = (blockIdx.x * 256 + threadIdx.x) * 4;
    if (i + 3 < n) {
        float4 v = *(const float4*)(src + i);
        ushort4 o = make_ushort4(f2bf(v.x), f2bf(v.y), f2bf(v.z), f2bf(v.w));
        *(ushort4*)(dst + i) = o;
    }
}

// ---------------------------------------------------------------------------
// transpose4: W[k][n] fp32 (1024x1024) -> Wt[n][k] bf16, for 4 weights.
// ---------------------------------------------------------------------------
__global__ __launch_bounds__(256) void transpose4_kernel(
    const float* __restrict__ w0, const float* __restrict__ w1,
    const float* __restrict__ w2, const float* __restrict__ w3,
    ushort_t* __restrict__ o0, ushort_t* __restrict__ o1,
    ushort_t* __restrict__ o2, ushort_t* __restrict__ o3)
{
    __shared__ float tile[32][33];
    const float* W = (blockIdx.z == 0) ? w0 : (blockIdx.z == 1) ? w1
                   : (blockIdx.z == 2) ? w2 : w3;
    ushort_t* O = (blockIdx.z == 0) ? o0 : (blockIdx.z == 1) ? o1
                : (blockIdx.z == 2) ? o2 : o3;
    const int tx = threadIdx.x & 31;
    const int ty = threadIdx.x >> 5;
    const int kbase = blockIdx.y * 32;
    const int nbase = blockIdx.x * 32;
    #pragma unroll
    for (int j = 0; j < 4; ++j)
        tile[ty + 8 * j][tx] = W[(size_t)(kbase + ty + 8 * j) * 1024 + nbase + tx];
    __syncthreads();
    #pragma unroll
    for (int j = 0; j < 4; ++j) {
        int n = nbase + ty + 8 * j;
        O[(size_t)n * 1024 + kbase + tx] = f2bf(tile[tx][ty + 8 * j]);
    }
}

// ---------------------------------------------------------------------------
// bf16 MFMA GEMM body (B^T layout): out = A @ Bt^T [+ bvec] [+ res]
// BM=BN=64, BK=64, 256 threads, wave-tile 32x32 (2x2x2 of 16x16x32).
// OUT_VT: write output TRANSPOSED as vT[(b*16+h)][d][l] bf16 (b=row>>9,
// l=row&511, h=col>>6, d=col&63) -- feeds attention pass 2 with barrier-free
// global V^T fragment reads. 4 consecutive rows pack into one 8B store.
// ---------------------------------------------------------------------------
template <bool OUT_BF16, bool ADD_BVEC, bool ADD_RES, bool OUT_VT>
__device__ __forceinline__ void gemm_bt_body(
    const ushort_t* __restrict__ A, const ushort_t* __restrict__ Bt,
    const float* __restrict__ bvec, const float* __restrict__ res,
    void* __restrict__ outp, int N, int K, int kStart, int kEnd,
    int rowBase, int colBase, ushort_t* As, ushort_t* Bs)
{
    const int tid = threadIdx.x;
    const int l = tid & 63;
    const int w = tid >> 6;
    const int wave_m = w >> 1;
    const int wave_n = w & 1;

    const int srow8 = l >> 3;
    const int cgl = ((l & 7) + srow8) & 7;        // global k-chunk
    const ushort_t* gA0 = A  + (size_t)(rowBase + w * 16 + 0 + srow8) * K + cgl * 8;
    const ushort_t* gA1 = A  + (size_t)(rowBase + w * 16 + 8 + srow8) * K + cgl * 8;
    const ushort_t* gB0 = Bt + (size_t)(colBase + w * 16 + 0 + srow8) * K + cgl * 8;
    const ushort_t* gB1 = Bt + (size_t)(colBase + w * 16 + 8 + srow8) * K + cgl * 8;
    ushort_t* lA0 = As + w * 1024;
    ushort_t* lA1 = As + w * 1024 + 512;
    ushort_t* lB0 = Bs + w * 1024;
    ushort_t* lB1 = Bs + w * 1024 + 512;

    floatx4 acc[2][2];
    #pragma unroll
    for (int i = 0; i < 2; ++i)
        #pragma unroll
        for (int j = 0; j < 2; ++j)
            acc[i][j] = (floatx4){0.f, 0.f, 0.f, 0.f};

    const int fm = l & 15;
    const int fg = l >> 4;

    for (int k0 = kStart; k0 < kEnd; k0 += 64) {
        __builtin_amdgcn_global_load_lds(
            (const __attribute__((address_space(1))) void*)(gA0 + k0),
            (__attribute__((address_space(3))) void*)lA0, 16, 0, 0);
        __builtin_amdgcn_global_load_lds(
            (const __attribute__((address_space(1))) void*)(gA1 + k0),
            (__attribute__((address_space(3))) void*)lA1, 16, 0, 0);
        __builtin_amdgcn_global_load_lds(
            (const __attribute__((address_space(1))) void*)(gB0 + k0),
            (__attribute__((address_space(3))) void*)lB0, 16, 0, 0);
        __builtin_amdgcn_global_load_lds(
            (const __attribute__((address_space(1))) void*)(gB1 + k0),
            (__attribute__((address_space(3))) void*)lB1, 16, 0, 0);
        __syncthreads();

        short8 afrag[2][2], bfrag[2][2];
        #pragma unroll
        for (int mi = 0; mi < 2; ++mi)
            #pragma unroll
            for (int kt = 0; kt < 2; ++kt) {
                int p = ((kt * 4 + fg) - fm) & 7;
                afrag[mi][kt] = *(const short8*)
                    &As[(wave_m * 32 + mi * 16 + fm) * 64 + p * 8];
            }
        #pragma unroll
        for (int ni = 0; ni < 2; ++ni)
            #pragma unroll
            for (int kt = 0; kt < 2; ++kt) {
                int p = ((kt * 4 + fg) - fm) & 7;
                bfrag[ni][kt] = *(const short8*)
                    &Bs[(wave_n * 32 + ni * 16 + fm) * 64 + p * 8];
            }

        #pragma unroll
        for (int kt = 0; kt < 2; ++kt)
            #pragma unroll
            for (int mi = 0; mi < 2; ++mi)
                #pragma unroll
                for (int ni = 0; ni < 2; ++ni)
                    acc[mi][ni] = __builtin_amdgcn_mfma_f32_16x16x32_bf16(
                        afrag[mi][kt], bfrag[ni][kt], acc[mi][ni], 0, 0, 0);
        __syncthreads();
    }

    const int crow0 = rowBase + wave_m * 32 + fg * 4;
    const int ccol0 = colBase + wave_n * 32 + fm;
    #pragma unroll
    for (int mi = 0; mi < 2; ++mi) {
        #pragma unroll
        for (int ni = 0; ni < 2; ++ni) {
            const int col = ccol0 + ni * 16;
            const float bb = ADD_BVEC ? bvec[col] : 0.f;
            if (OUT_VT) {
                const int row0 = crow0 + mi * 16;   // rows row0..row0+3
                ushort4 pk;
                pk.x = f2bf(acc[mi][ni][0] + bb);
                pk.y = f2bf(acc[mi][ni][1] + bb);
                pk.z = f2bf(acc[mi][ni][2] + bb);
                pk.w = f2bf(acc[mi][ni][3] + bb);
                const size_t base =
                    ((size_t)((row0 >> 9) * 16 + (col >> 6)) * 64 + (col & 63)) * 512;
                *(ushort4*)&((ushort_t*)outp)[base + (row0 & 511)] = pk;
            } else {
                #pragma unroll
                for (int r = 0; r < 4; ++r) {
                    const int row = crow0 + mi * 16 + r;
                    float v = acc[mi][ni][r] + bb;
                    if (ADD_RES) v += res[(size_t)row * N + col];
                    if (OUT_BF16)
                        ((ushort_t*)outp)[(size_t)row * N + col] = f2bf(v);
                    else
                        ((float*)outp)[(size_t)row * N + col] = v;
                }
            }
        }
    }
}

// Batched QKV projection: blockIdx.z selects (A, Bt, bias, out). 1536 blocks.
// z==2 (V projection) writes its output transposed per-head (OUT_VT).
__global__ __launch_bounds__(256) void gemm_qkv(
    const ushort_t* a0, const ushort_t* a1, const ushort_t* a2,
    const ushort_t* t0, const ushort_t* t1, const ushort_t* t2,
    const float* b0, const float* b1, const float* b2,
    ushort_t* o0, ushort_t* o1, ushort_t* o2)
{
    __shared__ ushort_t As[64 * 64];
    __shared__ ushort_t Bs[64 * 64];
    const int z = blockIdx.z;
    if (z == 2) {
        gemm_bt_body<true, true, false, true>(a2, t2, b2, nullptr, o2, D_MODEL,
                                              D_MODEL, 0, D_MODEL,
                                              blockIdx.y * 64, blockIdx.x * 64, As, Bs);
    } else {
        const ushort_t* A  = (z == 0) ? a0 : a1;
        const ushort_t* Bt = (z == 0) ? t0 : t1;
        const float* bv    = (z == 0) ? b0 : b1;
        ushort_t* o        = (z == 0) ? o0 : o1;
        gemm_bt_body<true, true, false, false>(A, Bt, bv, nullptr, o, D_MODEL,
                                               D_MODEL, 0, D_MODEL,
                                               blockIdx.y * 64, blockIdx.x * 64, As, Bs);
    }
}

// Final projection, split-K x2.
__global__ __launch_bounds__(256) void gemm_out(
    const ushort_t* __restrict__ A, const ushort_t* __restrict__ Bt,
    const float* __restrict__ bvec, const float* __restrict__ res,
    float* __restrict__ out0, float* __restrict__ out1)
{
    __shared__ ushort_t As[64 * 64];
    __shared__ ushort_t Bs[64 * 64];
    if (blockIdx.z == 0)
        gemm_bt_body<false, true, true, false>(A, Bt, bvec, res, out0, D_MODEL,
                                               D_MODEL, 0, 512,
                                               blockIdx.y * 64, blockIdx.x * 64, As, Bs);
    else
        gemm_bt_body<false, false, false, false>(A, Bt, nullptr, nullptr, out1, D_MODEL,
                                                 D_MODEL, 512, 1024,
                                                 blockIdx.y * 64, blockIdx.x * 64, As, Bs);
}

// ---------------------------------------------------------------------------
// MFMA attention v5: block = 16 q-rows x one (b,h). 256 threads (4 waves).
// Structure of v4 (barrier-free pass 2 via globally-materialized V^T, only
// 3 barriers/block) with the spill fixed: __launch_bounds__(256,4) gives a
// 128-VGPR cap -- v4's (256,5)/102-cap made the compiler spill acc+bsum to
// scratch (VGPR_Count=32, WRITE_SIZE 4->135MB, +47MB FETCH, dur 76->115us).
// 4 blocks/CU x 19.5KB LDS = 78KB; 16 waves/CU.
// Grid: (LSEQ/16, BATCH*N_HEADS) = (32, 64).
// ---------------------------------------------------------------------------
#define P_STRIDE 520   // ushorts; 1040B row => row-start banks rotate by 4

__global__ __launch_bounds__(256, 4) void attn_mfma(
    const ushort_t* __restrict__ qh, const ushort_t* __restrict__ kh,
    const ushort_t* __restrict__ vt, const float* __restrict__ bias,
    const float* __restrict__ gbias, ushort_t* __restrict__ ctx)
{
    __shared__ __attribute__((aligned(16))) ushort_t Qs[16 * 72];
    __shared__ __attribute__((aligned(16))) ushort_t P[16 * P_STRIDE];
    __shared__ float redm[4][16];
    __shared__ float reds[4][16];

    const int tid = threadIdx.x;
    const int l = tid & 63;
    const int w = tid >> 6;
    const int m = l & 15;
    const int g = l >> 4;

    const int bh = blockIdx.y;
    const int h = bh & (N_HEADS - 1);
    const int b = bh >> 4;
    const int q0 = blockIdx.x * 16;

    const ushort_t* Qg = qh + ((size_t)(b * LSEQ + q0)) * D_MODEL + h * DK;
    const ushort_t* Kg = kh + ((size_t)(b * LSEQ)) * D_MODEL + h * DK;
    const ushort_t* Vt_g = vt + (size_t)bh * DK * LSEQ;   // [64][512] bf16

    // ---- stage Q tile (16 x 64 bf16) ----
    if (tid < 128) {
        int row = tid >> 3, seg = tid & 7;
        short8 t = *(const short8*)(Qg + (size_t)row * D_MODEL + seg * 8);
        *(short8*)&Qs[row * 72 + seg * 8] = t;
    }
    __syncthreads();

    short8 aq0 = *(const short8*)&Qs[m * 72 + g * 8];
    short8 aq1 = *(const short8*)&Qs[m * 72 + g * 8 + 32];

    // ---- pass 1: S = QK^T (K direct from global, no barriers) ----
    floatx4 acc[8];
    #pragma unroll 2
    for (int it = 0; it < 8; ++it) {
        const int kb = it * 64 + w * 16;
        const ushort_t* kr = Kg + (size_t)(kb + m) * D_MODEL + g * 8;
        short8 bk0 = *(const short8*)kr;
        short8 bk1 = *(const short8*)(kr + 32);
        floatx4 a = (floatx4){0.f, 0.f, 0.f, 0.f};
        a = __builtin_amdgcn_mfma_f32_16x16x32_bf16(aq0, bk0, a, 0, 0, 0);
        a = __builtin_amdgcn_mfma_f32_16x16x32_bf16(aq1, bk1, a, 0, 0, 0);
        acc[it] = a;
    }

    // ---- bias + gbias in MFMA C-layout: thread (w,g,m) owns
    // rows g*4+r, cols it*64 + w*16 + m. 64 independent dword loads. ----
    const float* bp = bias  + ((size_t)bh * LSEQ + q0) * LSEQ + w * 16 + m;
    const float* gp = gbias + ((size_t)bh * LSEQ + q0) * LSEQ + w * 16 + m;
    float bsum[8][4];
    #pragma unroll
    for (int it = 0; it < 8; ++it)
        #pragma unroll
        for (int r = 0; r < 4; ++r) {
            const size_t off = (size_t)(g * 4 + r) * LSEQ + it * 64;
            bsum[it][r] = bp[off] + gp[off];
        }
    #pragma unroll
    for (int it = 0; it < 8; ++it)
        #pragma unroll
        for (int r = 0; r < 4; ++r)
            acc[it][r] = acc[it][r] * 0.125f + bsum[it][r];

    // ---- softmax in MFMA layout ----
    float mx[4];
    #pragma unroll
    for (int r = 0; r < 4; ++r) {
        float pm = fmaxf(
            fmaxf(fmaxf(acc[0][r], acc[1][r]), fmaxf(acc[2][r], acc[3][r])),
            fmaxf(fmaxf(acc[4][r], acc[5][r]), fmaxf(acc[6][r], acc[7][r])));
        #pragma unroll
        for (int d = 1; d < 16; d <<= 1)
            pm = fmaxf(pm, __shfl_xor(pm, d, 64));
        mx[r] = pm;
    }
    if (m == 0) {
        #pragma unroll
        for (int r = 0; r < 4; ++r) redm[w][g * 4 + r] = mx[r];
    }
    __syncthreads();
    #pragma unroll
    for (int r = 0; r < 4; ++r)
        mx[r] = fmaxf(fmaxf(redm[0][g * 4 + r], redm[1][g * 4 + r]),
                      fmaxf(redm[2][g * 4 + r], redm[3][g * 4 + r]));

    float sm[4] = {0.f, 0.f, 0.f, 0.f};
    #pragma unroll
    for (int it = 0; it < 8; ++it)
        #pragma unroll
        for (int r = 0; r < 4; ++r) {
            float e = __expf(acc[it][r] - mx[r]);
            sm[r] += e;
            P[(g * 4 + r) * P_STRIDE + it * 64 + w * 16 + m] = f2bf(e);
        }
    #pragma unroll
    for (int r = 0; r < 4; ++r) {
        #pragma unroll
        for (int d = 1; d < 16; d <<= 1)
            sm[r] += __shfl_xor(sm[r], d, 64);
    }
    if (m == 0) {
        #pragma unroll
        for (int r = 0; r < 4; ++r) reds[w][g * 4 + r] = sm[r];
    }
    __syncthreads();   // publishes P + reds
    float rinv[4];
    #pragma unroll
    for (int r = 0; r < 4; ++r)
        rinv[r] = 1.0f / (reds[0][g * 4 + r] + reds[1][g * 4 + r] +
                          reds[2][g * 4 + r] + reds[3][g * 4 + r]);

    // ---- pass 2: ctx = P V. P from LDS, V^T direct from global.
    // Barrier-free: mirrors pass 1. Wave w owns output cols w*16+m. ----
    floatx4 oacc = (floatx4){0.f, 0.f, 0.f, 0.f};
    const ushort_t* vrow = Vt_g + (size_t)(w * 16 + m) * LSEQ + g * 8;
    const ushort_t* prow = &P[(size_t)m * P_STRIDE + g * 8];
    #pragma unroll 2
    for (int vtile = 0; vtile < 8; ++vtile) {
        #pragma unroll
        for (int kt = 0; kt < 2; ++kt) {
            const int ko = vtile * 64 + kt * 32;
            short8 pf = *(const short8*)(prow + ko);
            short8 vf = *(const short8*)(vrow + ko);
            oacc = __builtin_amdgcn_mfma_f32_16x16x32_bf16(pf, vf, oacc, 0, 0, 0);
        }
    }

    // ---- epilogue: row g*4+r matches rinv[r] held in this lane ----
    {
        const int qrow0 = g * 4;
        const int dcol = w * 16 + m;
        ushort_t* cp = ctx + ((size_t)(b * LSEQ + q0 + qrow0)) * D_MODEL + h * DK + dcol;
        #pragma unroll
        for (int r = 0; r < 4; ++r)
            cp[(size_t)r * D_MODEL] = f2bf(oacc[r] * rinv[r]);
    }
}

// ---------------------------------------------------------------------------
// LayerNorm over D=1024: x = LN(x + part2). One block per row.
// ---------------------------------------------------------------------------
__global__ __launch_bounds__(256) void ln_kernel(
    float* __restrict__ x, const float* __restrict__ part2,
    const float* __restrict__ g, const float* __restrict__ beta)
{
    const int row = blockIdx.x;
    float* xr = x + (size_t)row * D_MODEL;
    const float* pr = part2 + (size_t)row * D_MODEL;
    const int tid = threadIdx.x;

    float v[4];
    float s = 0.f, sq = 0.f;
    #pragma unroll
    for (int j = 0; j < 4; ++j) {
        v[j] = xr[tid + 256 * j] + pr[tid + 256 * j];
        s += v[j];
        sq += v[j] * v[j];
    }
    __shared__ float rs[256], rq[256];
    rs[tid] = s;
    rq[tid] = sq;
    __syncthreads();
    for (int st = 128; st > 0; st >>= 1) {
        if (tid < st) { rs[tid] += rs[tid + st]; rq[tid] += rq[tid + st]; }
        __syncthreads();
    }
    const float mean = rs[0] * (1.0f / D_MODEL);
    const float var = rq[0] * (1.0f / D_MODEL) - mean * mean;
    const float rinv = rsqrtf(var + 1e-6f);
    #pragma unroll
    for (int j = 0; j < 4; ++j) {
        int n = tid + 256 * j;
        xr[n] = (v[j] - mean) * rinv * g[n] + beta[n];
    }
}

// ---------------------------------------------------------------------------
extern "C" void kernel_launch(void* const* d_in, const int* in_sizes, int n_in,
                              void* d_out, int out_size, void* d_ws, size_t ws_size,
                              hipStream_t stream)
{
    const float* q     = (const float*)d_in[0];
    const float* k     = (const float*)d_in[1];
    const float* v     = (const float*)d_in[2];
    const float* bias  = (const float*)d_in[3];
    const float* gbias = (const float*)d_in[4];
    const float* wq    = (const float*)d_in[5];
    const float* bq    = (const float*)d_in[6];
    const float* wk    = (const float*)d_in[7];
    const float* bk    = (const float*)d_in[8];
    const float* wv    = (const float*)d_in[9];
    const float* bv    = (const float*)d_in[10];
    const float* wo    = (const float*)d_in[11];
    const float* bo    = (const float*)d_in[12];
    const float* ln_g  = (const float*)d_in[13];
    const float* ln_b  = (const float*)d_in[14];

    const size_t MB = 1u << 20;
    char* wsb = (char*)d_ws;
    ushort_t* vb   = (ushort_t*)(wsb + 0 * MB);    // 4 MB
    ushort_t* wqb  = (ushort_t*)(wsb + 4 * MB);    // 2 MB each
    ushort_t* wkb  = (ushort_t*)(wsb + 6 * MB);
    ushort_t* wvb  = (ushort_t*)(wsb + 8 * MB);
    ushort_t* wob  = (ushort_t*)(wsb + 10 * MB);
    ushort_t* qhb  = (ushort_t*)(wsb + 12 * MB);   // 4 MB each
    ushort_t* khb  = (ushort_t*)(wsb + 16 * MB);
    ushort_t* vtb  = (ushort_t*)(wsb + 20 * MB);   // V^T [bh][64][512]
    ushort_t* ctxb = (ushort_t*)(wsb + 24 * MB);
    // out1 (8 MB fp32) overlays qhb+khb — both dead once attn completes.
    float* out1 = (float*)(wsb + 12 * MB);
    // d_out doubles as qb/kb scratch; dead before gemm_out writes d_out.
    ushort_t* qb = (ushort_t*)d_out;
    ushort_t* kb = (ushort_t*)d_out + (size_t)M_ROWS * D_MODEL;
    float* outp = (float*)d_out;

    const int NELEM = M_ROWS * D_MODEL;

    cast3_kernel<<<dim3(NELEM / 1024, 3), 256, 0, stream>>>(
        q, k, v, qb, kb, vb, NELEM);
    transpose4_kernel<<<dim3(32, 32, 4), 256, 0, stream>>>(
        wq, wk, wv, wo, wqb, wkb, wvb, wob);

    dim3 gqkv(D_MODEL / 64, M_ROWS / 64, 3);  // 1536 blocks
    gemm_qkv<<<gqkv, 256, 0, stream>>>(
        qb, kb, vb, wqb, wkb, wvb, bq, bk, bv, qhb, khb, vtb);

    dim3 ablk(LSEQ / 16, BATCH * N_HEADS);    // 2048 blocks
    attn_mfma<<<ablk, 256, 0, stream>>>(qhb, khb, vtb, bias, gbias, ctxb);

    dim3 gout(D_MODEL / 64, M_ROWS / 64, 2);  // 1024 blocks (split-K x2)
    gemm_out<<<gout, 256, 0, stream>>>(ctxb, wob, bo, q, outp, out1);

    ln_kernel<<<M_ROWS, 256, 0, stream>>>(outp, out1, ln_g, ln_b);
}